// Round 5
// baseline (238.729 us; speedup 1.0000x reference)
//
#include <hip/hip_runtime.h>
#include <hip/hip_bf16.h>

// Problem constants
#define N_TOT 32768
#define G 4
#define DIM 128
#define CB 512
#define BM 64            // rows per block; 4 waves x 128 cols = full CB per block

// Output layout (floats)
#define XHAT_OFF   0
#define ONEHOT_OFF ((size_t)N_TOT * G * DIM)                      // 16777216
#define IDX_OFF    (ONEHOT_OFF + (size_t)N_TOT * G * CB)          // 83886080

// Workspace layout (bytes)
#define CB2_BYTES  ((size_t)G * CB * 4)                            // 8192
#define CBH_OFF    CB2_BYTES
#define CBHALF_BYTES ((size_t)G * CB * DIM * 2)                    // 524288
#define CBL_OFF    (CBH_OFF + CBHALF_BYTES)
#define XH_OFF     (CBL_OFF + CBHALF_BYTES)                        // 1056768
#define XHALF_BYTES ((size_t)N_TOT * G * DIM * 2)                  // 33554432
#define XL_OFF     (XH_OFF + XHALF_BYTES)
#define WS_NEED    (XL_OFF + XHALF_BYTES)                          // ~68.2 MB

typedef _Float16 half8    __attribute__((ext_vector_type(8)));
typedef _Float16 half4    __attribute__((ext_vector_type(4)));
typedef float    floatx16 __attribute__((ext_vector_type(16)));
typedef float    floatx4  __attribute__((ext_vector_type(4)));

// fp32 -> (hi,lo) fp16 RN split. f = hi + lo + err, |err| <= 2^-22 |f|.
__device__ __forceinline__ void split4(float4 v, half4& hi, half4& lo) {
    float f[4] = {v.x, v.y, v.z, v.w};
#pragma unroll
    for (int e = 0; e < 4; ++e) {
        _Float16 h = (_Float16)f[e];
        hi[e] = h;
        lo[e] = (_Float16)(f[e] - (float)h);
    }
}
__device__ __forceinline__ void split8(floatx4 v0, floatx4 v1, half8& hi, half8& lo) {
    float f[8] = {v0.x, v0.y, v0.z, v0.w, v1.x, v1.y, v1.z, v1.w};
#pragma unroll
    for (int e = 0; e < 8; ++e) {
        _Float16 h = (_Float16)f[e];
        hi[e] = h;
        lo[e] = (_Float16)(f[e] - (float)h);
    }
}

// ---------------------------------------------------------------------------
// Prep A: cb2h + cb hi/lo split (one thread per [g,k] codebook row)
// ---------------------------------------------------------------------------
__global__ void cvq_cbprep_kernel(const float* __restrict__ cb, float* __restrict__ cb2h,
                                  _Float16* __restrict__ cbh, _Float16* __restrict__ cbl) {
    int i = blockIdx.x * 256 + threadIdx.x;   // 0 .. G*CB-1
    if (i >= G * CB) return;
    const float4* p = (const float4*)&cb[(size_t)i * DIM];
    float s = 0.f;
#pragma unroll
    for (int j = 0; j < DIM / 4; ++j) {
        float4 v = p[j];
        s += v.x * v.x + v.y * v.y + v.z * v.z + v.w * v.w;
        half4 h, l;
        split4(v, h, l);
        *(half4*)&cbh[(size_t)i * DIM + j * 4] = h;
        *(half4*)&cbl[(size_t)i * DIM + j * 4] = l;
    }
    cb2h[i] = 0.5f * s;
}

// ---------------------------------------------------------------------------
// Prep B: x hi/lo split (one thread per float4)
// ---------------------------------------------------------------------------
__global__ void cvq_xsplit_kernel(const float* __restrict__ x,
                                  _Float16* __restrict__ xh, _Float16* __restrict__ xl) {
    size_t i = (size_t)blockIdx.x * 256 + threadIdx.x;   // float4 index
    float4 v = ((const float4*)x)[i];
    half4 h, l;
    split4(v, h, l);
    ((half4*)xh)[i] = h;
    ((half4*)xl)[i] = l;
}

// ---------------------------------------------------------------------------
// Fast main kernel: pre-split inputs, pure load->MFMA inner loop.
// Block = (64 n-rows, one group g), 4 waves; wave w -> cols w*128..+127.
// score = 0.5*cb2[k] - cross  (same argmin as reference dist).
// Fragment layouts (gfx950 32x32x16): A row=l&31,k=(l>>5)*8+e; B col=l&31;
// C col=l&31, row=(r&3)+8*(r>>2)+4*(l>>5)   [m74/m101]
// ---------------------------------------------------------------------------
__global__ __launch_bounds__(256, 2) void cvq_main_split_kernel(
        const _Float16* __restrict__ xh, const _Float16* __restrict__ xl,
        const _Float16* __restrict__ cbh, const _Float16* __restrict__ cbl,
        const float* __restrict__ cb, const float* __restrict__ cb2h,
        float* __restrict__ out) {

    __shared__ float part_v[4][BM];
    __shared__ int   part_i[4][BM];
    __shared__ int   idxs[BM];

    const int n0   = blockIdx.x * BM;
    const int g    = blockIdx.y;
    const int tid  = threadIdx.x;
    const int wid  = tid >> 6;
    const int lane = tid & 63;
    const int col  = lane & 31;
    const int h    = lane >> 5;
    const int klo  = h * 8;

    const size_t a0 = (((size_t)(n0 + col)) * G + g) * DIM + klo;
    const size_t a1 = (((size_t)(n0 + 32 + col)) * G + g) * DIM + klo;
    size_t boff[4];
#pragma unroll
    for (int t = 0; t < 4; ++t)
        boff[t] = ((size_t)g * CB + wid * 128 + t * 32 + col) * DIM + klo;

    floatx16 acc[2][4] = {};   // [mtile][ntile] fp32 accumulators = cross

#pragma unroll
    for (int ks = 0; ks < 8; ++ks) {
        const int d = ks * 16;
        half8 ah[2], al[2];
        ah[0] = *(const half8*)&xh[a0 + d];
        al[0] = *(const half8*)&xl[a0 + d];
        ah[1] = *(const half8*)&xh[a1 + d];
        al[1] = *(const half8*)&xl[a1 + d];
#pragma unroll
        for (int t = 0; t < 4; ++t) {
            half8 bh = *(const half8*)&cbh[boff[t] + d];
            half8 bl = *(const half8*)&cbl[boff[t] + d];
#pragma unroll
            for (int mt = 0; mt < 2; ++mt) {
                acc[mt][t] = __builtin_amdgcn_mfma_f32_32x32x16_f16(ah[mt], bh, acc[mt][t], 0, 0, 0);
                acc[mt][t] = __builtin_amdgcn_mfma_f32_32x32x16_f16(ah[mt], bl, acc[mt][t], 0, 0, 0);
                acc[mt][t] = __builtin_amdgcn_mfma_f32_32x32x16_f16(al[mt], bh, acc[mt][t], 0, 0, 0);
            }
        }
    }

    // ---- per-row argmin over this wave's 128 cols ----
    float c2v[4];
#pragma unroll
    for (int t = 0; t < 4; ++t)
        c2v[t] = cb2h[g * CB + wid * 128 + t * 32 + col];

#pragma unroll
    for (int mt = 0; mt < 2; ++mt) {
#pragma unroll
        for (int r = 0; r < 16; ++r) {
            const int row = mt * 32 + (r & 3) + 8 * (r >> 2) + 4 * h;
            float bv = c2v[0] - acc[mt][0][r];
            int   bi = wid * 128 + col;
#pragma unroll
            for (int t = 1; t < 4; ++t) {
                float sc = c2v[t] - acc[mt][t][r];
                int   kk = wid * 128 + t * 32 + col;
                if (sc < bv) { bv = sc; bi = kk; }
            }
#pragma unroll
            for (int off = 1; off < 32; off <<= 1) {
                float ov = __shfl_xor(bv, off);
                int   oi = __shfl_xor(bi, off);
                if (ov < bv || (ov == bv && oi < bi)) { bv = ov; bi = oi; }
            }
            if (col == 0) { part_v[wid][row] = bv; part_i[wid][row] = bi; }
        }
    }
    __syncthreads();

    if (tid < BM) {
        float bv = part_v[0][tid];
        int   bi = part_i[0][tid];
#pragma unroll
        for (int w = 1; w < 4; ++w) {
            float pv = part_v[w][tid];
            int   pi = part_i[w][tid];
            if (pv < bv || (pv == bv && pi < bi)) { bv = pv; bi = pi; }
        }
        idxs[tid] = bi;
        out[IDX_OFF + (size_t)(n0 + tid) * G + g] = (float)bi;
    }
    __syncthreads();

    float* out_xhat = out + XHAT_OFF;
    float* out_oh   = out + ONEHOT_OFF;

#pragma unroll
    for (int p = 0; p < 8; ++p) {
        int t  = tid + p * 256;
        int r  = t >> 5;
        int d4 = (t & 31) << 2;
        int k  = idxs[r];
        floatx4 v = *(const floatx4*)&cb[((size_t)g * CB + k) * DIM + d4];
        __builtin_nontemporal_store(v, (floatx4*)&out_xhat[(((size_t)(n0 + r)) * G + g) * DIM + d4]);
    }

#pragma unroll
    for (int p = 0; p < 32; ++p) {
        int t  = tid + p * 256;
        int r  = t >> 7;
        int k4 = (t & 127) << 2;
        int k  = idxs[r];
        floatx4 v;
        v.x = (k4 + 0 == k) ? 1.f : 0.f;
        v.y = (k4 + 1 == k) ? 1.f : 0.f;
        v.z = (k4 + 2 == k) ? 1.f : 0.f;
        v.w = (k4 + 3 == k) ? 1.f : 0.f;
        __builtin_nontemporal_store(v, (floatx4*)&out_oh[(((size_t)(n0 + r)) * G + g) * CB + k4]);
    }
}

// ---------------------------------------------------------------------------
// FALLBACK (validated round-4 path): in-kernel splits, used if ws too small.
// ---------------------------------------------------------------------------
__global__ void cvq_cb2_kernel(const float* __restrict__ cb, float* __restrict__ cb2h) {
    int i = blockIdx.x * 256 + threadIdx.x;
    if (i >= G * CB) return;
    const float4* p = (const float4*)&cb[(size_t)i * DIM];
    float s = 0.f;
#pragma unroll
    for (int j = 0; j < DIM / 4; ++j) {
        float4 v = p[j];
        s += v.x * v.x + v.y * v.y + v.z * v.z + v.w * v.w;
    }
    cb2h[i] = 0.5f * s;
}

__global__ __launch_bounds__(256, 2) void cvq_main_kernel(
        const float* __restrict__ x,
        const float* __restrict__ cb,
        const float* __restrict__ cb2h,
        float* __restrict__ out) {

    __shared__ float part_v[4][BM];
    __shared__ int   part_i[4][BM];
    __shared__ int   idxs[BM];

    const int n0   = blockIdx.x * BM;
    const int g    = blockIdx.y;
    const int tid  = threadIdx.x;
    const int wid  = tid >> 6;
    const int lane = tid & 63;
    const int col  = lane & 31;
    const int h    = lane >> 5;
    const int klo  = h * 8;

    const float* xr0 = &x[(((size_t)(n0 + col)) * G + g) * DIM + klo];
    const float* xr1 = &x[(((size_t)(n0 + 32 + col)) * G + g) * DIM + klo];
    const float* cbr[4];
#pragma unroll
    for (int t = 0; t < 4; ++t)
        cbr[t] = &cb[((size_t)g * CB + wid * 128 + t * 32 + col) * DIM + klo];

    floatx16 acc[2][4] = {};

#pragma unroll
    for (int ks = 0; ks < 8; ++ks) {
        const int d = ks * 16;
        half8 ah[2], al[2];
        split8(*(const floatx4*)(xr0 + d), *(const floatx4*)(xr0 + d + 4), ah[0], al[0]);
        split8(*(const floatx4*)(xr1 + d), *(const floatx4*)(xr1 + d + 4), ah[1], al[1]);
#pragma unroll
        for (int t = 0; t < 4; ++t) {
            half8 bh, bl;
            split8(*(const floatx4*)(cbr[t] + d), *(const floatx4*)(cbr[t] + d + 4), bh, bl);
#pragma unroll
            for (int mt = 0; mt < 2; ++mt) {
                acc[mt][t] = __builtin_amdgcn_mfma_f32_32x32x16_f16(ah[mt], bh, acc[mt][t], 0, 0, 0);
                acc[mt][t] = __builtin_amdgcn_mfma_f32_32x32x16_f16(ah[mt], bl, acc[mt][t], 0, 0, 0);
                acc[mt][t] = __builtin_amdgcn_mfma_f32_32x32x16_f16(al[mt], bh, acc[mt][t], 0, 0, 0);
            }
        }
    }

    float c2v[4];
#pragma unroll
    for (int t = 0; t < 4; ++t)
        c2v[t] = cb2h[g * CB + wid * 128 + t * 32 + col];

#pragma unroll
    for (int mt = 0; mt < 2; ++mt) {
#pragma unroll
        for (int r = 0; r < 16; ++r) {
            const int row = mt * 32 + (r & 3) + 8 * (r >> 2) + 4 * h;
            float bv = c2v[0] - acc[mt][0][r];
            int   bi = wid * 128 + col;
#pragma unroll
            for (int t = 1; t < 4; ++t) {
                float sc = c2v[t] - acc[mt][t][r];
                int   kk = wid * 128 + t * 32 + col;
                if (sc < bv) { bv = sc; bi = kk; }
            }
#pragma unroll
            for (int off = 1; off < 32; off <<= 1) {
                float ov = __shfl_xor(bv, off);
                int   oi = __shfl_xor(bi, off);
                if (ov < bv || (ov == bv && oi < bi)) { bv = ov; bi = oi; }
            }
            if (col == 0) { part_v[wid][row] = bv; part_i[wid][row] = bi; }
        }
    }
    __syncthreads();

    if (tid < BM) {
        float bv = part_v[0][tid];
        int   bi = part_i[0][tid];
#pragma unroll
        for (int w = 1; w < 4; ++w) {
            float pv = part_v[w][tid];
            int   pi = part_i[w][tid];
            if (pv < bv || (pv == bv && pi < bi)) { bv = pv; bi = pi; }
        }
        idxs[tid] = bi;
        out[IDX_OFF + (size_t)(n0 + tid) * G + g] = (float)bi;
    }
    __syncthreads();

    float* out_xhat = out + XHAT_OFF;
    float* out_oh   = out + ONEHOT_OFF;

#pragma unroll
    for (int p = 0; p < 8; ++p) {
        int t  = tid + p * 256;
        int r  = t >> 5;
        int d4 = (t & 31) << 2;
        int k  = idxs[r];
        floatx4 v = *(const floatx4*)&cb[((size_t)g * CB + k) * DIM + d4];
        __builtin_nontemporal_store(v, (floatx4*)&out_xhat[(((size_t)(n0 + r)) * G + g) * DIM + d4]);
    }

#pragma unroll
    for (int p = 0; p < 32; ++p) {
        int t  = tid + p * 256;
        int r  = t >> 7;
        int k4 = (t & 127) << 2;
        int k  = idxs[r];
        floatx4 v;
        v.x = (k4 + 0 == k) ? 1.f : 0.f;
        v.y = (k4 + 1 == k) ? 1.f : 0.f;
        v.z = (k4 + 2 == k) ? 1.f : 0.f;
        v.w = (k4 + 3 == k) ? 1.f : 0.f;
        __builtin_nontemporal_store(v, (floatx4*)&out_oh[(((size_t)(n0 + r)) * G + g) * CB + k4]);
    }
}

extern "C" void kernel_launch(void* const* d_in, const int* in_sizes, int n_in,
                              void* d_out, int out_size, void* d_ws, size_t ws_size,
                              hipStream_t stream) {
    const float* x  = (const float*)d_in[0];
    const float* cb = (const float*)d_in[1];
    float* out = (float*)d_out;
    char*  ws  = (char*)d_ws;
    float* cb2h = (float*)ws;

    if (ws_size >= WS_NEED) {
        _Float16* cbh = (_Float16*)(ws + CBH_OFF);
        _Float16* cbl = (_Float16*)(ws + CBL_OFF);
        _Float16* xh  = (_Float16*)(ws + XH_OFF);
        _Float16* xl  = (_Float16*)(ws + XL_OFF);
        cvq_cbprep_kernel<<<dim3((G * CB + 255) / 256), dim3(256), 0, stream>>>(cb, cb2h, cbh, cbl);
        cvq_xsplit_kernel<<<dim3((unsigned)((size_t)N_TOT * G * DIM / 4 / 256)), dim3(256), 0, stream>>>(x, xh, xl);
        cvq_main_split_kernel<<<dim3(N_TOT / BM, G), dim3(256), 0, stream>>>(xh, xl, cbh, cbl, cb, cb2h, out);
    } else {
        cvq_cb2_kernel<<<dim3((G * CB + 255) / 256), dim3(256), 0, stream>>>(cb, cb2h);
        cvq_main_kernel<<<dim3(N_TOT / BM, G), dim3(256), 0, stream>>>(x, cb, cb2h, out);
    }
}

// Round 7
// 195.948 us; speedup vs baseline: 1.2183x; 1.2183x over previous
//
#include <hip/hip_runtime.h>
#include <hip/hip_bf16.h>

// Problem constants
#define N_TOT 32768
#define G 4
#define DIM 128
#define CB 512
#define BM 32            // rows per block; 4 waves, each 32 rows x 128 cols

// Output layout (floats)
#define XHAT_OFF   0
#define ONEHOT_OFF ((size_t)N_TOT * G * DIM)                      // 16777216
#define IDX_OFF    (ONEHOT_OFF + (size_t)N_TOT * G * CB)          // 83886080

// Workspace layout (bytes): cb2h + pre-split codebook hi/lo
#define CB2_BYTES    ((size_t)G * CB * 4)                          // 8192
#define CBH_OFF      CB2_BYTES
#define CBHALF_BYTES ((size_t)G * CB * DIM * 2)                    // 524288
#define CBL_OFF      (CBH_OFF + CBHALF_BYTES)
#define WS_NEED      (CBL_OFF + CBHALF_BYTES)                      // ~1.06 MB

typedef _Float16 half8    __attribute__((ext_vector_type(8)));
typedef _Float16 half4    __attribute__((ext_vector_type(4)));
typedef float    floatx16 __attribute__((ext_vector_type(16)));
typedef float    floatx4  __attribute__((ext_vector_type(4)));

// fp32 -> (hi,lo) fp16 RN split. f = hi + lo + err, |err| <= 2^-22 |f|.
__device__ __forceinline__ void split4(float4 v, half4& hi, half4& lo) {
    float f[4] = {v.x, v.y, v.z, v.w};
#pragma unroll
    for (int e = 0; e < 4; ++e) {
        _Float16 h = (_Float16)f[e];
        hi[e] = h;
        lo[e] = (_Float16)(f[e] - (float)h);
    }
}
__device__ __forceinline__ void split8(floatx4 v0, floatx4 v1, half8& hi, half8& lo) {
    float f[8] = {v0.x, v0.y, v0.z, v0.w, v1.x, v1.y, v1.z, v1.w};
#pragma unroll
    for (int e = 0; e < 8; ++e) {
        _Float16 h = (_Float16)f[e];
        hi[e] = h;
        lo[e] = (_Float16)(f[e] - (float)h);
    }
}

// ---------------------------------------------------------------------------
// Prep: cb2h + cb hi/lo split (one thread per [g,k] codebook row) — ~2 us
// ---------------------------------------------------------------------------
__global__ void cvq_cbprep_kernel(const float* __restrict__ cb, float* __restrict__ cb2h,
                                  _Float16* __restrict__ cbh, _Float16* __restrict__ cbl) {
    int i = blockIdx.x * 256 + threadIdx.x;   // 0 .. G*CB-1
    if (i >= G * CB) return;
    const float4* p = (const float4*)&cb[(size_t)i * DIM];
    float s = 0.f;
#pragma unroll
    for (int j = 0; j < DIM / 4; ++j) {
        float4 v = p[j];
        s += v.x * v.x + v.y * v.y + v.z * v.z + v.w * v.w;
        half4 h, l;
        split4(v, h, l);
        *(half4*)&cbh[(size_t)i * DIM + j * 4] = h;
        *(half4*)&cbl[(size_t)i * DIM + j * 4] = l;
    }
    cb2h[i] = 0.5f * s;
}

// ---------------------------------------------------------------------------
// Main kernel: block = (32 n-rows, one group g), 4 waves.
// Wave w: rows n0..n0+31 x cols w*128..+127 via v_mfma_f32_32x32x16_f16,
// fp16x3 split (x split in-kernel, cb pre-split). acc[4] = 64 AGPRs ->
// __launch_bounds__(256,3) -> 3 waves/SIMD for latency hiding.
// score = 0.5*cb2[k] - cross  (same argmin as reference dist).
// Fragment layouts (gfx950 32x32x16, validated rounds 4-5):
//   A: lane l, elem e: row=l&31, k=(l>>5)*8+e ; B: col=l&31, same k
//   C: lane l, reg r:  col=l&31, row=(r&3)+8*(r>>2)+4*(l>>5)
// ---------------------------------------------------------------------------
__global__ __launch_bounds__(256, 3) void cvq_main32_kernel(
        const float* __restrict__ x,
        const _Float16* __restrict__ cbh, const _Float16* __restrict__ cbl,
        const float* __restrict__ cb, const float* __restrict__ cb2h,
        float* __restrict__ out) {

    __shared__ float part_v[4][BM];
    __shared__ int   part_i[4][BM];
    __shared__ int   idxs[BM];

    const int n0   = blockIdx.x * BM;
    const int g    = blockIdx.y;
    const int tid  = threadIdx.x;
    const int wid  = tid >> 6;        // wave 0..3 -> cols wid*128..+127
    const int lane = tid & 63;
    const int col  = lane & 31;
    const int h    = lane >> 5;
    const int klo  = h * 8;

    const float* xr = &x[(((size_t)(n0 + col)) * G + g) * DIM + klo];
    size_t boff[4];
#pragma unroll
    for (int t = 0; t < 4; ++t)
        boff[t] = ((size_t)g * CB + wid * 128 + t * 32 + col) * DIM + klo;

    floatx16 acc[4] = {};   // [ntile] fp32 accumulators = cross

#pragma unroll
    for (int ks = 0; ks < 8; ++ks) {
        const int d = ks * 16;
        half8 ah, al;
        split8(*(const floatx4*)(xr + d), *(const floatx4*)(xr + d + 4), ah, al);
#pragma unroll
        for (int t = 0; t < 4; ++t) {
            half8 bh = *(const half8*)&cbh[boff[t] + d];
            half8 bl = *(const half8*)&cbl[boff[t] + d];
            acc[t] = __builtin_amdgcn_mfma_f32_32x32x16_f16(ah, bh, acc[t], 0, 0, 0);
            acc[t] = __builtin_amdgcn_mfma_f32_32x32x16_f16(ah, bl, acc[t], 0, 0, 0);
            acc[t] = __builtin_amdgcn_mfma_f32_32x32x16_f16(al, bh, acc[t], 0, 0, 0);
        }
    }

    // ---- per-row argmin over this wave's 128 cols ----
    float c2v[4];
#pragma unroll
    for (int t = 0; t < 4; ++t)
        c2v[t] = cb2h[g * CB + wid * 128 + t * 32 + col];

#pragma unroll
    for (int r = 0; r < 16; ++r) {
        const int row = (r & 3) + 8 * (r >> 2) + 4 * h;   // 0..31
        float bv = c2v[0] - acc[0][r];
        int   bi = wid * 128 + col;
#pragma unroll
        for (int t = 1; t < 4; ++t) {
            float sc = c2v[t] - acc[t][r];
            int   kk = wid * 128 + t * 32 + col;
            if (sc < bv) { bv = sc; bi = kk; }            // k ascending in t
        }
        // reduce across the 32 cols (xor offsets stay within 32-lane half)
#pragma unroll
        for (int off = 1; off < 32; off <<= 1) {
            float ov = __shfl_xor(bv, off);
            int   oi = __shfl_xor(bi, off);
            if (ov < bv || (ov == bv && oi < bi)) { bv = ov; bi = oi; }
        }
        if (col == 0) { part_v[wid][row] = bv; part_i[wid][row] = bi; }
    }
    __syncthreads();

    // ---- combine the 4 waves' col-slices (ascending wave = ascending k) ----
    if (tid < BM) {
        float bv = part_v[0][tid];
        int   bi = part_i[0][tid];
#pragma unroll
        for (int w = 1; w < 4; ++w) {
            float pv = part_v[w][tid];
            int   pi = part_i[w][tid];
            if (pv < bv || (pv == bv && pi < bi)) { bv = pv; bi = pi; }
        }
        idxs[tid] = bi;
        out[IDX_OFF + (size_t)(n0 + tid) * G + g] = (float)bi;
    }
    __syncthreads();

    float* out_xhat = out + XHAT_OFF;
    float* out_oh   = out + ONEHOT_OFF;

    // ---- x_hat: 32 rows x 32 float4 ----
#pragma unroll
    for (int p = 0; p < 4; ++p) {
        int t  = tid + p * 256;
        int r  = t >> 5;
        int d4 = (t & 31) << 2;
        int k  = idxs[r];
        floatx4 v = *(const floatx4*)&cb[((size_t)g * CB + k) * DIM + d4];
        __builtin_nontemporal_store(v, (floatx4*)&out_xhat[(((size_t)(n0 + r)) * G + g) * DIM + d4]);
    }

    // ---- one_hot: 32 rows x 128 float4, fused zero-fill ----
#pragma unroll
    for (int p = 0; p < 16; ++p) {
        int t  = tid + p * 256;
        int r  = t >> 7;
        int k4 = (t & 127) << 2;
        int k  = idxs[r];
        floatx4 v;
        v.x = (k4 + 0 == k) ? 1.f : 0.f;
        v.y = (k4 + 1 == k) ? 1.f : 0.f;
        v.z = (k4 + 2 == k) ? 1.f : 0.f;
        v.w = (k4 + 3 == k) ? 1.f : 0.f;
        __builtin_nontemporal_store(v, (floatx4*)&out_oh[(((size_t)(n0 + r)) * G + g) * CB + k4]);
    }
}

// ---------------------------------------------------------------------------
// FALLBACK (validated round-4 path, needs only 8KB ws): in-kernel splits.
// ---------------------------------------------------------------------------
#define FBM 64
__global__ void cvq_cb2_kernel(const float* __restrict__ cb, float* __restrict__ cb2h) {
    int i = blockIdx.x * 256 + threadIdx.x;
    if (i >= G * CB) return;
    const float4* p = (const float4*)&cb[(size_t)i * DIM];
    float s = 0.f;
#pragma unroll
    for (int j = 0; j < DIM / 4; ++j) {
        float4 v = p[j];
        s += v.x * v.x + v.y * v.y + v.z * v.z + v.w * v.w;
    }
    cb2h[i] = 0.5f * s;
}

__global__ __launch_bounds__(256, 2) void cvq_main_kernel(
        const float* __restrict__ x,
        const float* __restrict__ cb,
        const float* __restrict__ cb2h,
        float* __restrict__ out) {

    __shared__ float part_v[4][FBM];
    __shared__ int   part_i[4][FBM];
    __shared__ int   idxs[FBM];

    const int n0   = blockIdx.x * FBM;
    const int g    = blockIdx.y;
    const int tid  = threadIdx.x;
    const int wid  = tid >> 6;
    const int lane = tid & 63;
    const int col  = lane & 31;
    const int h    = lane >> 5;
    const int klo  = h * 8;

    const float* xr0 = &x[(((size_t)(n0 + col)) * G + g) * DIM + klo];
    const float* xr1 = &x[(((size_t)(n0 + 32 + col)) * G + g) * DIM + klo];
    const float* cbr[4];
#pragma unroll
    for (int t = 0; t < 4; ++t)
        cbr[t] = &cb[((size_t)g * CB + wid * 128 + t * 32 + col) * DIM + klo];

    floatx16 acc[2][4] = {};

#pragma unroll
    for (int ks = 0; ks < 8; ++ks) {
        const int d = ks * 16;
        half8 ah[2], al[2];
        split8(*(const floatx4*)(xr0 + d), *(const floatx4*)(xr0 + d + 4), ah[0], al[0]);
        split8(*(const floatx4*)(xr1 + d), *(const floatx4*)(xr1 + d + 4), ah[1], al[1]);
#pragma unroll
        for (int t = 0; t < 4; ++t) {
            half8 bh, bl;
            split8(*(const floatx4*)(cbr[t] + d), *(const floatx4*)(cbr[t] + d + 4), bh, bl);
#pragma unroll
            for (int mt = 0; mt < 2; ++mt) {
                acc[mt][t] = __builtin_amdgcn_mfma_f32_32x32x16_f16(ah[mt], bh, acc[mt][t], 0, 0, 0);
                acc[mt][t] = __builtin_amdgcn_mfma_f32_32x32x16_f16(ah[mt], bl, acc[mt][t], 0, 0, 0);
                acc[mt][t] = __builtin_amdgcn_mfma_f32_32x32x16_f16(al[mt], bh, acc[mt][t], 0, 0, 0);
            }
        }
    }

    float c2v[4];
#pragma unroll
    for (int t = 0; t < 4; ++t)
        c2v[t] = cb2h[g * CB + wid * 128 + t * 32 + col];

#pragma unroll
    for (int mt = 0; mt < 2; ++mt) {
#pragma unroll
        for (int r = 0; r < 16; ++r) {
            const int row = mt * 32 + (r & 3) + 8 * (r >> 2) + 4 * h;
            float bv = c2v[0] - acc[mt][0][r];
            int   bi = wid * 128 + col;
#pragma unroll
            for (int t = 1; t < 4; ++t) {
                float sc = c2v[t] - acc[mt][t][r];
                int   kk = wid * 128 + t * 32 + col;
                if (sc < bv) { bv = sc; bi = kk; }
            }
#pragma unroll
            for (int off = 1; off < 32; off <<= 1) {
                float ov = __shfl_xor(bv, off);
                int   oi = __shfl_xor(bi, off);
                if (ov < bv || (ov == bv && oi < bi)) { bv = ov; bi = oi; }
            }
            if (col == 0) { part_v[wid][row] = bv; part_i[wid][row] = bi; }
        }
    }
    __syncthreads();

    if (tid < FBM) {
        float bv = part_v[0][tid];
        int   bi = part_i[0][tid];
#pragma unroll
        for (int w = 1; w < 4; ++w) {
            float pv = part_v[w][tid];
            int   pi = part_i[w][tid];
            if (pv < bv || (pv == bv && pi < bi)) { bv = pv; bi = pi; }
        }
        idxs[tid] = bi;
        out[IDX_OFF + (size_t)(n0 + tid) * G + g] = (float)bi;
    }
    __syncthreads();

    float* out_xhat = out + XHAT_OFF;
    float* out_oh   = out + ONEHOT_OFF;

#pragma unroll
    for (int p = 0; p < 8; ++p) {
        int t  = tid + p * 256;
        int r  = t >> 5;
        int d4 = (t & 31) << 2;
        int k  = idxs[r];
        floatx4 v = *(const floatx4*)&cb[((size_t)g * CB + k) * DIM + d4];
        __builtin_nontemporal_store(v, (floatx4*)&out_xhat[(((size_t)(n0 + r)) * G + g) * DIM + d4]);
    }

#pragma unroll
    for (int p = 0; p < 32; ++p) {
        int t  = tid + p * 256;
        int r  = t >> 7;
        int k4 = (t & 127) << 2;
        int k  = idxs[r];
        floatx4 v;
        v.x = (k4 + 0 == k) ? 1.f : 0.f;
        v.y = (k4 + 1 == k) ? 1.f : 0.f;
        v.z = (k4 + 2 == k) ? 1.f : 0.f;
        v.w = (k4 + 3 == k) ? 1.f : 0.f;
        __builtin_nontemporal_store(v, (floatx4*)&out_oh[(((size_t)(n0 + r)) * G + g) * CB + k4]);
    }
}

extern "C" void kernel_launch(void* const* d_in, const int* in_sizes, int n_in,
                              void* d_out, int out_size, void* d_ws, size_t ws_size,
                              hipStream_t stream) {
    const float* x  = (const float*)d_in[0];
    const float* cb = (const float*)d_in[1];
    float* out = (float*)d_out;
    char*  ws  = (char*)d_ws;
    float* cb2h = (float*)ws;

    if (ws_size >= WS_NEED) {
        _Float16* cbh = (_Float16*)(ws + CBH_OFF);
        _Float16* cbl = (_Float16*)(ws + CBL_OFF);
        cvq_cbprep_kernel<<<dim3((G * CB + 255) / 256), dim3(256), 0, stream>>>(cb, cb2h, cbh, cbl);
        cvq_main32_kernel<<<dim3(N_TOT / BM, G), dim3(256), 0, stream>>>(x, cbh, cbl, cb, cb2h, out);
    } else {
        cvq_cb2_kernel<<<dim3((G * CB + 255) / 256), dim3(256), 0, stream>>>(cb, cb2h);
        cvq_main_kernel<<<dim3(N_TOT / FBM, G), dim3(256), 0, stream>>>(x, cb, cb2h, out);
    }
}

// Round 8
// 154.633 us; speedup vs baseline: 1.5438x; 1.2672x over previous
//
#include <hip/hip_runtime.h>
#include <hip/hip_bf16.h>

// Problem constants
#define N_TOT 32768
#define G 4
#define DIM 128
#define CB 512
#define BM 32            // rows per block; 4 waves, each 32 rows x 128 cols

// Output layout (floats)
#define XHAT_OFF   0
#define ONEHOT_OFF ((size_t)N_TOT * G * DIM)                      // 16777216
#define IDX_OFF    (ONEHOT_OFF + (size_t)N_TOT * G * CB)          // 83886080

// Workspace layout (bytes): cb2h + fragment-packed codebook hi/lo planes
// cbf layout: [g][colblk(16)][ks(8)][h(2)][col(32)][e(8)] fp16
//   -> per (g,colblk): 4096 halfs; per ks: 512 halfs; lane offset = lane*8
#define CB2_BYTES    ((size_t)G * CB * 4)                          // 8192
#define CBH_OFF      CB2_BYTES
#define CBHALF_BYTES ((size_t)G * CB * DIM * 2)                    // 524288
#define CBL_OFF      (CBH_OFF + CBHALF_BYTES)
#define WS_NEED      (CBL_OFF + CBHALF_BYTES)                      // ~1.06 MB

typedef _Float16 half8    __attribute__((ext_vector_type(8)));
typedef _Float16 half4    __attribute__((ext_vector_type(4)));
typedef float    floatx16 __attribute__((ext_vector_type(16)));
typedef float    floatx4  __attribute__((ext_vector_type(4)));

// fp32 -> (hi,lo) fp16 RN split. f = hi + lo + err, |err| <= 2^-22 |f|.
__device__ __forceinline__ void split8(floatx4 v0, floatx4 v1, half8& hi, half8& lo) {
    float f[8] = {v0.x, v0.y, v0.z, v0.w, v1.x, v1.y, v1.z, v1.w};
#pragma unroll
    for (int e = 0; e < 8; ++e) {
        _Float16 h = (_Float16)f[e];
        hi[e] = h;
        lo[e] = (_Float16)(f[e] - (float)h);
    }
}

// ---------------------------------------------------------------------------
// Prep 1: cb2h[g*CB+k] = 0.5*sum_d cb[g][k][d]^2  (validated since round 1)
// ---------------------------------------------------------------------------
__global__ void cvq_cb2_kernel(const float* __restrict__ cb, float* __restrict__ cb2h) {
    int i = blockIdx.x * 256 + threadIdx.x;
    if (i >= G * CB) return;
    const float4* p = (const float4*)&cb[(size_t)i * DIM];
    float s = 0.f;
#pragma unroll
    for (int j = 0; j < DIM / 4; ++j) {
        float4 v = p[j];
        s += v.x * v.x + v.y * v.y + v.z * v.z + v.w * v.w;
    }
    cb2h[i] = 0.5f * s;
}

// ---------------------------------------------------------------------------
// Prep 2: pack codebook into MFMA-fragment order, split hi/lo.
// thread tid_global = ((((g*16+colblk)*8+ks)*2+h)*32+col), 0..32767
// reads cb[g][colblk*32+col][ks*16+h*8 .. +8] (32B), writes half8 at tid*8
// (writes fully coalesced; reads are 32B-granular gathers, one-pass, tiny)
// ---------------------------------------------------------------------------
__global__ void cvq_cbpack_kernel(const float* __restrict__ cb,
                                  _Float16* __restrict__ cbfh, _Float16* __restrict__ cbfl) {
    int t = blockIdx.x * 256 + threadIdx.x;    // 0..32767
    int col    = t & 31;
    int h      = (t >> 5) & 1;
    int ks     = (t >> 6) & 7;
    int colblk = (t >> 9) & 15;
    int g      = t >> 13;
    const float* src = &cb[((size_t)(g * CB + colblk * 32 + col)) * DIM + ks * 16 + h * 8];
    half8 hi, lo;
    split8(*(const floatx4*)src, *(const floatx4*)(src + 4), hi, lo);
    *(half8*)&cbfh[(size_t)t * 8] = hi;
    *(half8*)&cbfl[(size_t)t * 8] = lo;
}

// ---------------------------------------------------------------------------
// Main kernel: block = (32 n-rows, one group g), 4 waves; wave w -> cols
// w*128..+127. x staged in LDS (coalesced, XOR chunk swizzle c^=r&7), split
// to fp16 in-kernel; cb fragment loads are single 1024B coalesced wave-loads.
// score = 0.5*cb2[k] - cross  (same argmin as reference dist).
// Fragment layouts (gfx950 32x32x16, validated rounds 4-7):
//   A: lane l, elem e: row=l&31, k=(l>>5)*8+e ; B: col=l&31, same k
//   C: lane l, reg r:  col=l&31, row=(r&3)+8*(r>>2)+4*(l>>5)
// ---------------------------------------------------------------------------
__global__ __launch_bounds__(256, 3) void cvq_main_packed_kernel(
        const float* __restrict__ x,
        const _Float16* __restrict__ cbfh, const _Float16* __restrict__ cbfl,
        const float* __restrict__ cb, const float* __restrict__ cb2h,
        float* __restrict__ out) {

    __shared__ float xs[BM * DIM];    // 16 KB, float4-chunk swizzled
    __shared__ float part_v[4][BM];
    __shared__ int   part_i[4][BM];
    __shared__ int   idxs[BM];

    const int n0   = blockIdx.x * BM;
    const int g    = blockIdx.y;
    const int tid  = threadIdx.x;
    const int wid  = tid >> 6;        // wave 0..3 -> cols wid*128..+127
    const int lane = tid & 63;
    const int col  = lane & 31;
    const int h    = lane >> 5;

    // ---- stage x tile: 32 rows x 128 floats, coalesced; chunk c -> c^(r&7) ----
#pragma unroll
    for (int p = 0; p < 4; ++p) {
        int t = tid + p * 256;         // 0..1023 = 32 rows * 32 float4-chunks
        int r = t >> 5;
        int c = t & 31;
        floatx4 v = *(const floatx4*)&x[(((size_t)(n0 + r)) * G + g) * DIM + (c << 2)];
        *(floatx4*)&xs[r * DIM + ((c ^ (r & 7)) << 2)] = v;
    }
    __syncthreads();

    // cbf base for this wave: (g*16 + wid*4 + t)*4096 + ks*512 + lane*8
    const size_t cb_base = ((size_t)g * 16 + wid * 4) * 4096 + (size_t)lane * 8;

    floatx16 acc[4] = {};   // [ntile] fp32 accumulators = cross

#pragma unroll
    for (int ks = 0; ks < 8; ++ks) {
        // A fragment: row=col, k = ks*16 + h*8 .. +8  -> chunks c0, c0+1
        const int c0 = ks * 4 + h * 2;
        const int base = col * DIM;
        const int s = col & 7;
        floatx4 xa = *(const floatx4*)&xs[base + ((c0 ^ s) << 2)];
        floatx4 xb = *(const floatx4*)&xs[base + (((c0 + 1) ^ s) << 2)];
        half8 ah, al;
        split8(xa, xb, ah, al);
#pragma unroll
        for (int t = 0; t < 4; ++t) {
            const size_t o = cb_base + (size_t)t * 4096 + ks * 512;
            half8 bh = *(const half8*)&cbfh[o];
            half8 bl = *(const half8*)&cbfl[o];
            acc[t] = __builtin_amdgcn_mfma_f32_32x32x16_f16(ah, bh, acc[t], 0, 0, 0);
            acc[t] = __builtin_amdgcn_mfma_f32_32x32x16_f16(ah, bl, acc[t], 0, 0, 0);
            acc[t] = __builtin_amdgcn_mfma_f32_32x32x16_f16(al, bh, acc[t], 0, 0, 0);
        }
    }

    // ---- per-row argmin over this wave's 128 cols (validated round 7) ----
    float c2v[4];
#pragma unroll
    for (int t = 0; t < 4; ++t)
        c2v[t] = cb2h[g * CB + wid * 128 + t * 32 + col];

#pragma unroll
    for (int r = 0; r < 16; ++r) {
        const int row = (r & 3) + 8 * (r >> 2) + 4 * h;   // 0..31
        float bv = c2v[0] - acc[0][r];
        int   bi = wid * 128 + col;
#pragma unroll
        for (int t = 1; t < 4; ++t) {
            float sc = c2v[t] - acc[t][r];
            int   kk = wid * 128 + t * 32 + col;
            if (sc < bv) { bv = sc; bi = kk; }            // k ascending in t
        }
#pragma unroll
        for (int off = 1; off < 32; off <<= 1) {
            float ov = __shfl_xor(bv, off);
            int   oi = __shfl_xor(bi, off);
            if (ov < bv || (ov == bv && oi < bi)) { bv = ov; bi = oi; }
        }
        if (col == 0) { part_v[wid][row] = bv; part_i[wid][row] = bi; }
    }
    __syncthreads();

    // ---- combine the 4 waves' col-slices (ascending wave = ascending k) ----
    if (tid < BM) {
        float bv = part_v[0][tid];
        int   bi = part_i[0][tid];
#pragma unroll
        for (int w = 1; w < 4; ++w) {
            float pv = part_v[w][tid];
            int   pi = part_i[w][tid];
            if (pv < bv || (pv == bv && pi < bi)) { bv = pv; bi = pi; }
        }
        idxs[tid] = bi;
        out[IDX_OFF + (size_t)(n0 + tid) * G + g] = (float)bi;
    }
    __syncthreads();

    float* out_xhat = out + XHAT_OFF;
    float* out_oh   = out + ONEHOT_OFF;

    // ---- x_hat: 32 rows x 32 float4 ----
#pragma unroll
    for (int p = 0; p < 4; ++p) {
        int t  = tid + p * 256;
        int r  = t >> 5;
        int d4 = (t & 31) << 2;
        int k  = idxs[r];
        floatx4 v = *(const floatx4*)&cb[((size_t)g * CB + k) * DIM + d4];
        __builtin_nontemporal_store(v, (floatx4*)&out_xhat[(((size_t)(n0 + r)) * G + g) * DIM + d4]);
    }

    // ---- one_hot: 32 rows x 128 float4, fused zero-fill ----
#pragma unroll
    for (int p = 0; p < 16; ++p) {
        int t  = tid + p * 256;
        int r  = t >> 7;
        int k4 = (t & 127) << 2;
        int k  = idxs[r];
        floatx4 v;
        v.x = (k4 + 0 == k) ? 1.f : 0.f;
        v.y = (k4 + 1 == k) ? 1.f : 0.f;
        v.z = (k4 + 2 == k) ? 1.f : 0.f;
        v.w = (k4 + 3 == k) ? 1.f : 0.f;
        __builtin_nontemporal_store(v, (floatx4*)&out_oh[(((size_t)(n0 + r)) * G + g) * CB + k4]);
    }
}

// ---------------------------------------------------------------------------
// FALLBACK (validated round-4 path, needs only 8KB ws): in-kernel splits.
// ---------------------------------------------------------------------------
#define FBM 64
__global__ __launch_bounds__(256, 2) void cvq_main_kernel(
        const float* __restrict__ x,
        const float* __restrict__ cb,
        const float* __restrict__ cb2h,
        float* __restrict__ out) {

    __shared__ float part_v[4][FBM];
    __shared__ int   part_i[4][FBM];
    __shared__ int   idxs[FBM];

    const int n0   = blockIdx.x * FBM;
    const int g    = blockIdx.y;
    const int tid  = threadIdx.x;
    const int wid  = tid >> 6;
    const int lane = tid & 63;
    const int col  = lane & 31;
    const int h    = lane >> 5;
    const int klo  = h * 8;

    const float* xr0 = &x[(((size_t)(n0 + col)) * G + g) * DIM + klo];
    const float* xr1 = &x[(((size_t)(n0 + 32 + col)) * G + g) * DIM + klo];
    const float* cbr[4];
#pragma unroll
    for (int t = 0; t < 4; ++t)
        cbr[t] = &cb[((size_t)g * CB + wid * 128 + t * 32 + col) * DIM + klo];

    floatx16 acc[2][4] = {};

#pragma unroll
    for (int ks = 0; ks < 8; ++ks) {
        const int d = ks * 16;
        half8 ah[2], al[2];
        split8(*(const floatx4*)(xr0 + d), *(const floatx4*)(xr0 + d + 4), ah[0], al[0]);
        split8(*(const floatx4*)(xr1 + d), *(const floatx4*)(xr1 + d + 4), ah[1], al[1]);
#pragma unroll
        for (int t = 0; t < 4; ++t) {
            half8 bh, bl;
            split8(*(const floatx4*)(cbr[t] + d), *(const floatx4*)(cbr[t] + d + 4), bh, bl);
#pragma unroll
            for (int mt = 0; mt < 2; ++mt) {
                acc[mt][t] = __builtin_amdgcn_mfma_f32_32x32x16_f16(ah[mt], bh, acc[mt][t], 0, 0, 0);
                acc[mt][t] = __builtin_amdgcn_mfma_f32_32x32x16_f16(ah[mt], bl, acc[mt][t], 0, 0, 0);
                acc[mt][t] = __builtin_amdgcn_mfma_f32_32x32x16_f16(al[mt], bh, acc[mt][t], 0, 0, 0);
            }
        }
    }

    float c2v[4];
#pragma unroll
    for (int t = 0; t < 4; ++t)
        c2v[t] = cb2h[g * CB + wid * 128 + t * 32 + col];

#pragma unroll
    for (int mt = 0; mt < 2; ++mt) {
#pragma unroll
        for (int r = 0; r < 16; ++r) {
            const int row = mt * 32 + (r & 3) + 8 * (r >> 2) + 4 * h;
            float bv = c2v[0] - acc[mt][0][r];
            int   bi = wid * 128 + col;
#pragma unroll
            for (int t = 1; t < 4; ++t) {
                float sc = c2v[t] - acc[mt][t][r];
                int   kk = wid * 128 + t * 32 + col;
                if (sc < bv) { bv = sc; bi = kk; }
            }
#pragma unroll
            for (int off = 1; off < 32; off <<= 1) {
                float ov = __shfl_xor(bv, off);
                int   oi = __shfl_xor(bi, off);
                if (ov < bv || (ov == bv && oi < bi)) { bv = ov; bi = oi; }
            }
            if (col == 0) { part_v[wid][row] = bv; part_i[wid][row] = bi; }
        }
    }
    __syncthreads();

    if (tid < FBM) {
        float bv = part_v[0][tid];
        int   bi = part_i[0][tid];
#pragma unroll
        for (int w = 1; w < 4; ++w) {
            float pv = part_v[w][tid];
            int   pi = part_i[w][tid];
            if (pv < bv || (pv == bv && pi < bi)) { bv = pv; bi = pi; }
        }
        idxs[tid] = bi;
        out[IDX_OFF + (size_t)(n0 + tid) * G + g] = (float)bi;
    }
    __syncthreads();

    float* out_xhat = out + XHAT_OFF;
    float* out_oh   = out + ONEHOT_OFF;

#pragma unroll
    for (int p = 0; p < 8; ++p) {
        int t  = tid + p * 256;
        int r  = t >> 5;
        int d4 = (t & 31) << 2;
        int k  = idxs[r];
        floatx4 v = *(const floatx4*)&cb[((size_t)g * CB + k) * DIM + d4];
        __builtin_nontemporal_store(v, (floatx4*)&out_xhat[(((size_t)(n0 + r)) * G + g) * DIM + d4]);
    }

#pragma unroll
    for (int p = 0; p < 32; ++p) {
        int t  = tid + p * 256;
        int r  = t >> 7;
        int k4 = (t & 127) << 2;
        int k  = idxs[r];
        floatx4 v;
        v.x = (k4 + 0 == k) ? 1.f : 0.f;
        v.y = (k4 + 1 == k) ? 1.f : 0.f;
        v.z = (k4 + 2 == k) ? 1.f : 0.f;
        v.w = (k4 + 3 == k) ? 1.f : 0.f;
        __builtin_nontemporal_store(v, (floatx4*)&out_oh[(((size_t)(n0 + r)) * G + g) * CB + k4]);
    }
}

extern "C" void kernel_launch(void* const* d_in, const int* in_sizes, int n_in,
                              void* d_out, int out_size, void* d_ws, size_t ws_size,
                              hipStream_t stream) {
    const float* x  = (const float*)d_in[0];
    const float* cb = (const float*)d_in[1];
    float* out = (float*)d_out;
    char*  ws  = (char*)d_ws;
    float* cb2h = (float*)ws;

    if (ws_size >= WS_NEED) {
        _Float16* cbfh = (_Float16*)(ws + CBH_OFF);
        _Float16* cbfl = (_Float16*)(ws + CBL_OFF);
        cvq_cb2_kernel<<<dim3((G * CB + 255) / 256), dim3(256), 0, stream>>>(cb, cb2h);
        cvq_cbpack_kernel<<<dim3(G * CB * 16 / 256), dim3(256), 0, stream>>>(cb, cbfh, cbfl);
        cvq_main_packed_kernel<<<dim3(N_TOT / BM, G), dim3(256), 0, stream>>>(x, cbfh, cbfl, cb, cb2h, out);
    } else {
        cvq_cb2_kernel<<<dim3((G * CB + 255) / 256), dim3(256), 0, stream>>>(cb, cb2h);
        cvq_main_kernel<<<dim3(N_TOT / FBM, G), dim3(256), 0, stream>>>(x, cb, cb2h, out);
    }
}